// Round 18
// baseline (64.509 us; speedup 1.0000x reference)
//
#include <hip/hip_runtime.h>

// ---------------------------------------------------------------------------
// AuxModelImageRotation round 18 = R16 (61.6 best) + mega smem 32KB only
// (R17's conv3 BM=64 reverted — it was the regression: halved MFMA/staging
// ratio and doubled B-tile staging; occupancy gain didn't pay for it).
//  K1 prep_w1r (97). K2 mega (3825, 32KB smem): conv1 | rot(nt) | w2r | w3r.
//  K3 conv2_fc1wr (904). K4 conv3 (288, BM=128). K5 fc1 (4,8,16). K6 fc2.
// Output: [logits 1024][labels 256][rotated 256*3*128*128] f32.
// ---------------------------------------------------------------------------

typedef short bf16x8 __attribute__((ext_vector_type(8)));
typedef float f32x4  __attribute__((ext_vector_type(4)));

__device__ __forceinline__ ushort f2bf(float f) {
    uint u = __float_as_uint(f);
    u += 0x7fffu + ((u >> 16) & 1u);
    return (ushort)(u >> 16);
}

__device__ __forceinline__ void nt_store4(float* p, f32x4 v) {
    __builtin_nontemporal_store(v, (f32x4*)p);
}

// async global->LDS, 16B per lane; dest linear (wave base + lane*16).
__device__ __forceinline__ void gload16(const void* g, void* l) {
    __builtin_amdgcn_global_load_lds(
        (const __attribute__((address_space(1))) unsigned int*)g,
        (__attribute__((address_space(3))) unsigned int*)l, 16, 0, 0);
}

// ---------------- K1: w1r + labels -----------------------------------------
__global__ __launch_bounds__(256) void prep_w1r(const float* __restrict__ w1,
                                                ushort* __restrict__ w1r,
                                                float* __restrict__ lab)
{
    const int bx = blockIdx.x, t = threadIdx.x;
    if (bx < 96) {                        // w1 rotated: [a*32+oc][ic*64+a8*8+b8]
        int i = bx * 256 + t;
        int n = i / 192, r = i - n * 192;
        int ic = r >> 6, a8 = (r >> 3) & 7, b8 = r & 7;
        int a = n >> 5, oc = n & 31;
        int kh, kw;
        switch (a) {
            case 0:  kh = a8;     kw = b8;     break;
            case 1:  kh = 7 - b8; kw = a8;     break;
            case 2:  kh = 7 - a8; kw = 7 - b8; break;
            default: kh = b8;     kw = 7 - a8; break;
        }
        w1r[i] = f2bf(w1[((oc * 3 + ic) * 8 + kh) * 8 + kw]);
    } else {
        lab[t] = (float)(t >> 6);
    }
}

// ---------------- K2: conv1 | rotation | w2r | w3r -------------------------
__global__ __launch_bounds__(256) void mega(const float* __restrict__ obs,
                                            const ushort* __restrict__ w1r,
                                            const float* __restrict__ b1,
                                            const float* __restrict__ w2,
                                            const float* __restrict__ w3,
                                            float* __restrict__ rot,
                                            ushort* __restrict__ act1,
                                            ushort* __restrict__ w2r,
                                            ushort* __restrict__ w3r)
{
    __shared__ __align__(16) char smem[32768];   // == conv1 need -> 5 blk/CU
    const int bx = blockIdx.x, t = threadIdx.x;

    if (bx < 481) {
        // ---- conv1: obs f32 -> act1 NHWC bf16, rotated weights (verified) -
        ushort* aT = (ushort*)smem;
        ushort* bT = (ushort*)(smem + 16384);
        const int m0  = bx * 128;
        const int wid = t >> 6, l = t & 63;
        const int lrow = l & 15, lk = (l >> 4) << 3;
        const int wm = (wid >> 1) * 64, wn = (wid & 1) * 64;

        int abase[4], aoff[4], bbase[4];
        #pragma unroll
        for (int j = 0; j < 4; ++j) {
            int cid = j * 256 + t;
            int row = cid >> 3, c = cid & 7;
            int m = m0 + row; m = m < 61504 ? m : 61503;
            int b = m / 961; int rem = m - b * 961;
            int p = rem / 31; int q = rem - p * 31;
            abase[j] = ((b * 3) << 14) + ((p * 4 + c) << 7) + q * 4;
            aoff[j]  = (row * 64 + c * 8) ^ ((row & 7) << 3);
            bbase[j] = row * 192 + c * 8;
        }

        f32x4 acc[4][4] = {};
        for (int ic = 0; ic < 3; ++ic) {
            #pragma unroll
            for (int j = 0; j < 4; ++j) {
                const float* src = obs + abase[j] + (ic << 14);
                float4 v0 = *(const float4*)src;
                float4 v1 = *(const float4*)(src + 4);
                bf16x8 pk;
                pk[0] = (short)f2bf(v0.x); pk[1] = (short)f2bf(v0.y);
                pk[2] = (short)f2bf(v0.z); pk[3] = (short)f2bf(v0.w);
                pk[4] = (short)f2bf(v1.x); pk[5] = (short)f2bf(v1.y);
                pk[6] = (short)f2bf(v1.z); pk[7] = (short)f2bf(v1.w);
                *(bf16x8*)&aT[aoff[j]] = pk;
            }
            #pragma unroll
            for (int j = 0; j < 4; ++j)
                *(bf16x8*)&bT[aoff[j]] = *(const bf16x8*)&w1r[bbase[j] + ic * 64];
            __syncthreads();
            #pragma unroll
            for (int s = 0; s < 2; ++s) {
                bf16x8 af[4], bv[4];
                #pragma unroll
                for (int m = 0; m < 4; ++m) {
                    int r = wm + m * 16 + lrow;
                    af[m] = *(const bf16x8*)&aT[(r * 64 + s * 32 + lk) ^ ((r & 7) << 3)];
                }
                #pragma unroll
                for (int n = 0; n < 4; ++n) {
                    int r = wn + n * 16 + lrow;
                    bv[n] = *(const bf16x8*)&bT[(r * 64 + s * 32 + lk) ^ ((r & 7) << 3)];
                }
                #pragma unroll
                for (int m = 0; m < 4; ++m)
                    #pragma unroll
                    for (int n = 0; n < 4; ++n)
                        acc[m][n] = __builtin_amdgcn_mfma_f32_16x16x32_bf16(af[m], bv[n], acc[m][n], 0, 0, 0);
            }
            __syncthreads();
        }
        #pragma unroll
        for (int m = 0; m < 4; ++m)
            #pragma unroll
            for (int j = 0; j < 4; ++j) {
                int row = m0 + wm + m * 16 + ((l >> 4) << 2) + j;
                if (row < 61504) {
                    int b = row / 961; int rem = row - b * 961;
                    int p = rem / 31;  int q = rem - p * 31;
                    #pragma unroll
                    for (int n = 0; n < 4; ++n) {
                        int col = wn + n * 16 + lrow;
                        int a = col >> 5, oc = col & 31;
                        int oh, ow;
                        switch (a) {
                            case 0:  oh = p;      ow = q;      break;
                            case 1:  oh = 30 - q; ow = p;      break;
                            case 2:  oh = 30 - p; ow = 30 - q; break;
                            default: oh = q;      ow = 30 - p; break;
                        }
                        float v = acc[m][n][j] + b1[oc];
                        v = v > 0.f ? v : 0.f;
                        act1[(((a << 6) + b) * 961 + oh * 31 + ow) * 32 + oc] = f2bf(v);
                    }
                }
            }
    } else if (bx < 3553) {
        // ---- rotation: 1-read-4-write, nt stores --------------------------
        float (*sN)[36] = (float(*)[36])smem;
        float (*sT)[33] = (float(*)[33])(smem + 4608);
        const int bb   = bx - 481;
        const int tile = bb & 15;
        const int cimg = bb >> 4;
        const int c = cimg % 3, b = cimg / 3;
        const int h0s = (tile >> 2) * 32, w0s = (tile & 3) * 32;
        const int rs = t >> 3, w4 = (t & 7) * 4;

        const float* src = obs + ((b * 3 + c) << 14);
        f32x4 v = *(const f32x4*)&src[((h0s + rs) << 7) + w0s + w4];
        *(f32x4*)&sN[rs][w4] = v;
        sT[w4 + 0][rs] = v.x; sT[w4 + 1][rs] = v.y;
        sT[w4 + 2][rs] = v.z; sT[w4 + 3][rs] = v.w;

        float* d0 = rot + (((      b) * 3 + c) << 14);
        float* d1 = rot + ((( 64 + b) * 3 + c) << 14);
        float* d2 = rot + (((128 + b) * 3 + c) << 14);
        float* d3 = rot + (((192 + b) * 3 + c) << 14);

        nt_store4(&d0[((h0s + rs) << 7) + w0s + w4], v);
        __syncthreads();
        f32x4 o;
        o.x = sT[31 - rs][w4 + 0]; o.y = sT[31 - rs][w4 + 1];
        o.z = sT[31 - rs][w4 + 2]; o.w = sT[31 - rs][w4 + 3];
        nt_store4(&d1[((96 - w0s + rs) << 7) + h0s + w4], o);
        o.x = sN[31 - rs][31 - w4 - 0]; o.y = sN[31 - rs][31 - w4 - 1];
        o.z = sN[31 - rs][31 - w4 - 2]; o.w = sN[31 - rs][31 - w4 - 3];
        nt_store4(&d2[((96 - h0s + rs) << 7) + (96 - w0s) + w4], o);
        o.x = sT[rs][31 - w4 - 0]; o.y = sT[rs][31 - w4 - 1];
        o.z = sT[rs][31 - w4 - 2]; o.w = sT[rs][31 - w4 - 3];
        nt_store4(&d3[((w0s + rs) << 7) + (96 - h0s) + w4], o);
    } else if (bx < 3681) {
        int i = (bx - 3553) * 256 + t;        // w2 -> (oc, kh, kw, ic) bf16
        int ic = i & 31, kw = (i >> 5) & 3, kh = (i >> 7) & 3, oc = i >> 9;
        w2r[i] = f2bf(w2[((oc * 32 + ic) * 4 + kh) * 4 + kw]);
    } else {
        int i = (bx - 3681) * 256 + t;        // w3 -> (oc, kh, kw, ic) bf16
        int ic = i & 63, r = i >> 6;
        int kw = r % 3, r2 = r / 3;
        int kh = r2 % 3, oc = r2 / 3;
        w3r[i] = f2bf(w3[((oc * 64 + ic) * 3 + kh) * 3 + kw]);
    }
}

// ---------------- conv body: gload_lds staging, source-swizzled ------------
template<int IC, int IH, int IW, int KH, int KW, int S, int OH, int OW>
__device__ __forceinline__ void conv_body(char* smem, int bid, int t,
                                          const ushort* __restrict__ in,
                                          const ushort* __restrict__ wr,
                                          const float* __restrict__ bias,
                                          ushort* __restrict__ out)
{
    constexpr int BK  = KW * IC;
    constexpr int NCH = BK / 8;
    constexpr int AJ  = 128 * NCH / 256;
    constexpr int BJ  = 64 * NCH / 256;
    ushort* aT = (ushort*)smem;               // 128*BK*2 B
    ushort* bT = (ushort*)(smem + 128 * BK * 2);
    const int m0 = bid * 128;
    const int wid = t >> 6, l = t & 63;
    const int lrow = l & 15, lk = (l >> 4) << 3;

    int asrc[AJ], bsrc[BJ];
    #pragma unroll
    for (int j = 0; j < AJ; ++j) {
        int tau = j * 256 + t;
        int row = tau / NCH, c = tau - row * NCH;
        int m   = m0 + row;
        int n   = m / (OH * OW); int rem = m - n * (OH * OW);
        int oh  = rem / OW; int ow = rem - oh * OW;
        asrc[j] = ((n * IH + oh * S) * IW + ow * S) * IC + (c ^ (row & 7)) * 8;
    }
    #pragma unroll
    for (int j = 0; j < BJ; ++j) {
        int tau = j * 256 + t;
        int row = tau / NCH, c = tau - row * NCH;
        bsrc[j] = row * (KH * BK) + (c ^ (row & 7)) * 8;
    }

    f32x4 acc[2][4] = {};
    for (int kh = 0; kh < KH; ++kh) {
        #pragma unroll
        for (int j = 0; j < AJ; ++j)
            gload16(in + asrc[j] + kh * (IW * IC), aT + (j * 256 + t) * 8);
        #pragma unroll
        for (int j = 0; j < BJ; ++j)
            gload16(wr + bsrc[j] + kh * BK, bT + (j * 256 + t) * 8);
        __syncthreads();
        #pragma unroll
        for (int s = 0; s < BK / 32; ++s) {
            bf16x8 af[2], bv[4];
            #pragma unroll
            for (int m = 0; m < 2; ++m) {
                int r = wid * 32 + m * 16 + lrow;
                af[m] = *(const bf16x8*)&aT[(r * BK + s * 32 + lk) ^ ((r & 7) << 3)];
            }
            #pragma unroll
            for (int n = 0; n < 4; ++n) {
                int r = n * 16 + lrow;
                bv[n] = *(const bf16x8*)&bT[(r * BK + s * 32 + lk) ^ ((r & 7) << 3)];
            }
            #pragma unroll
            for (int m = 0; m < 2; ++m)
                #pragma unroll
                for (int n = 0; n < 4; ++n)
                    acc[m][n] = __builtin_amdgcn_mfma_f32_16x16x32_bf16(af[m], bv[n], acc[m][n], 0, 0, 0);
        }
        __syncthreads();
    }
    #pragma unroll
    for (int m = 0; m < 2; ++m)
        #pragma unroll
        for (int n = 0; n < 4; ++n)
            #pragma unroll
            for (int j = 0; j < 4; ++j) {
                int row = m0 + wid * 32 + m * 16 + ((l >> 4) << 2) + j;
                int col = n * 16 + lrow;
                float v = acc[m][n][j] + bias[col];
                v = v > 0.f ? v : 0.f;
                out[row * 64 + col] = f2bf(v);
            }
}

// ---------------- K3: conv2 | fc1wr prep -----------------------------------
__global__ __launch_bounds__(256) void conv2_fc1wr(const ushort* __restrict__ act1,
                                                   const ushort* __restrict__ w2r,
                                                   const float* __restrict__ b2,
                                                   ushort* __restrict__ act2,
                                                   const float* __restrict__ fc1_w,
                                                   ushort* __restrict__ fc1wr)
{
    __shared__ __align__(16) char smem[49152];
    const int bx = blockIdx.x, t = threadIdx.x;
    if (bx < 392) {
        conv_body<32, 31, 31, 4, 4, 2, 14, 14>(smem, bx, t, act1, w2r, b2, act2);
    } else {
        // fc1_w [512][64*144] (c,p) -> bf16 (p,c), pad-145 LDS (verified)
        float* s = (float*)smem;
        const int n = bx - 392;
        #pragma unroll
        for (int j = 0; j < 9; ++j) {
            int i = (j * 256 + t) * 4;
            float4 v = *(const float4*)&fc1_w[n * 9216 + i];
            int ic = i / 144, p = i - ic * 144;
            s[ic * 145 + p + 0] = v.x; s[ic * 145 + p + 1] = v.y;
            s[ic * 145 + p + 2] = v.z; s[ic * 145 + p + 3] = v.w;
        }
        __syncthreads();
        uint* op = (uint*)(fc1wr + n * 9216);
        #pragma unroll
        for (int j = 0; j < 18; ++j) {
            int q  = j * 256 + t;
            int jj = q * 2;
            int ic = jj & 63, p = jj >> 6;
            uint lo = f2bf(s[ic * 145 + p]);
            uint hi = f2bf(s[(ic + 1) * 145 + p]);
            op[q] = lo | (hi << 16);
        }
    }
}

// ---------------- K4: conv3 (BM=128, 288 blocks) ---------------------------
__global__ __launch_bounds__(256) void conv3_k(const ushort* __restrict__ act2,
                                               const ushort* __restrict__ w3r,
                                               const float* __restrict__ b3,
                                               ushort* __restrict__ act3)
{
    __shared__ __align__(16) char smem[73728];
    conv_body<64, 14, 14, 3, 3, 1, 12, 12>(smem, blockIdx.x, threadIdx.x,
                                           act2, w3r, b3, act3);
}

// ---------------- fc1: gload_lds staging, split-K=16 -----------------------
__global__ __launch_bounds__(256) void fc1_mfma(const ushort* __restrict__ A,
                                                const ushort* __restrict__ W,
                                                float* __restrict__ hpart)
{
    __shared__ __align__(16) ushort aT[64 * 64];
    __shared__ __align__(16) ushort bT[64 * 64];
    const int t  = threadIdx.x;
    const int m0 = blockIdx.x * 64, n0 = blockIdx.y * 64;
    const int z  = blockIdx.z;                // 16 splits
    const int kb = z * 576;
    const int wid = t >> 6, l = t & 63;
    const int lrow = l & 15, lk = (l >> 4) << 3;
    const int wm = (wid >> 1) * 32, wn = (wid & 1) * 32;

    int asrcb[2], bsrcb[2];
    #pragma unroll
    for (int j = 0; j < 2; ++j) {
        int tau = j * 256 + t;
        int row = tau >> 3, c = tau & 7;
        int csw = (c ^ (row & 7)) * 8;
        asrcb[j] = (m0 + row) * 9216 + kb + csw;
        bsrcb[j] = (n0 + row) * 9216 + kb + csw;
    }

    f32x4 acc[2][2] = {};
    for (int k0 = 0; k0 < 576; k0 += 64) {
        #pragma unroll
        for (int j = 0; j < 2; ++j)
            gload16(A + asrcb[j] + k0, aT + (j * 256 + t) * 8);
        #pragma unroll
        for (int j = 0; j < 2; ++j)
            gload16(W + bsrcb[j] + k0, bT + (j * 256 + t) * 8);
        __syncthreads();
        #pragma unroll
        for (int s = 0; s < 2; ++s) {
            bf16x8 af[2], bv[2];
            #pragma unroll
            for (int m = 0; m < 2; ++m) {
                int r = wm + m * 16 + lrow;
                af[m] = *(const bf16x8*)&aT[(r * 64 + s * 32 + lk) ^ ((r & 7) << 3)];
            }
            #pragma unroll
            for (int n = 0; n < 2; ++n) {
                int r = wn + n * 16 + lrow;
                bv[n] = *(const bf16x8*)&bT[(r * 64 + s * 32 + lk) ^ ((r & 7) << 3)];
            }
            #pragma unroll
            for (int m = 0; m < 2; ++m)
                #pragma unroll
                for (int n = 0; n < 2; ++n)
                    acc[m][n] = __builtin_amdgcn_mfma_f32_16x16x32_bf16(af[m], bv[n], acc[m][n], 0, 0, 0);
        }
        __syncthreads();
    }
    #pragma unroll
    for (int m = 0; m < 2; ++m)
        #pragma unroll
        for (int n = 0; n < 2; ++n)
            #pragma unroll
            for (int j = 0; j < 4; ++j) {
                int row = m0 + wm + m * 16 + ((l >> 4) << 2) + j;
                int col = n0 + wn + n * 16 + lrow;
                hpart[(z * 256 + row) * 512 + col] = acc[m][n][j];
            }
}

// ---------------- fc2: combine 16 partials, bias, relu, final 512-dot ------
__global__ __launch_bounds__(256) void fc2_kernel(const float* __restrict__ hp,
                                                  const float* __restrict__ b1,
                                                  const float* __restrict__ W2,
                                                  const float* __restrict__ b2,
                                                  float* __restrict__ logits)
{
    __shared__ float s[512];
    const int i = blockIdx.x;
    const int t = threadIdx.x;
    for (int k = t; k < 512; k += 256) {
        float v = b1[k];
        #pragma unroll
        for (int z = 0; z < 16; ++z) v += hp[(z * 256 + i) * 512 + k];
        s[k] = v > 0.f ? v : 0.f;
    }
    __syncthreads();
    const int j = t >> 6;
    const int l = t & 63;
    float p = 0.f;
    #pragma unroll
    for (int q = 0; q < 8; ++q) p += s[l + q * 64] * W2[j * 512 + l + q * 64];
    #pragma unroll
    for (int off = 32; off > 0; off >>= 1) p += __shfl_xor(p, off);
    if (l == 0) logits[i * 4 + j] = p + b2[j];
}

// ---------------------------------------------------------------------------
extern "C" void kernel_launch(void* const* d_in, const int* in_sizes, int n_in,
                              void* d_out, int out_size, void* d_ws, size_t ws_size,
                              hipStream_t stream)
{
    const float* obs   = (const float*)d_in[0];
    const float* w1    = (const float*)d_in[1];
    const float* b1    = (const float*)d_in[2];
    const float* w2    = (const float*)d_in[3];
    const float* b2    = (const float*)d_in[4];
    const float* w3    = (const float*)d_in[5];
    const float* b3    = (const float*)d_in[6];
    const float* fc1_w = (const float*)d_in[7];
    const float* fc1_b = (const float*)d_in[8];
    const float* fc2_w = (const float*)d_in[9];
    const float* fc2_b = (const float*)d_in[10];

    float* out    = (float*)d_out;
    float* logits = out;
    float* labels = out + 1024;
    float* rot    = out + 1280;

    char* ws = (char*)d_ws;
    ushort* act1  = (ushort*)(ws);                       // 15,745,024 B (dead after conv2)
    float*  hpart = (float*) (ws);                       //  8,388,608 B (fc1/fc2 only)
    ushort* act2  = (ushort*)(ws + 15745024);            //  6,422,528 B
    ushort* act3  = (ushort*)(ws + 22167552);            //  4,718,592 B
    ushort* w2r   = (ushort*)(ws + 26886144);            //     65,536 B
    ushort* w3r   = (ushort*)(ws + 26951680);            //     73,728 B
    ushort* fc1wr = (ushort*)(ws + 27025408);            //  9,437,184 B
    ushort* w1r   = (ushort*)(ws + 40656896);            //     49,152 B

    prep_w1r<<<97, 256, 0, stream>>>(w1, w1r, labels);

    mega<<<3825, 256, 0, stream>>>(obs, w1r, b1, w2, w3,
                                   rot, act1, w2r, w3r);

    conv2_fc1wr<<<904, 256, 0, stream>>>(act1, w2r, b2, act2, fc1_w, fc1wr);

    conv3_k<<<288, 256, 0, stream>>>(act2, w3r, b3, act3);

    fc1_mfma<<<dim3(4, 8, 16), 256, 0, stream>>>(act3, fc1wr, hpart);
    fc2_kernel<<<256, 256, 0, stream>>>(hpart, fc1_b, fc2_w, fc2_b, logits);
}

// Round 19
// 61.612 us; speedup vs baseline: 1.0470x; 1.0470x over previous
//
#include <hip/hip_runtime.h>

// ---------------------------------------------------------------------------
// AuxModelImageRotation round 19 = exact R16 revert (best measured, 61.6us).
// R17/R18 established: mega-smem shrink and conv3 BM=64 are within-noise to
// negative; measurement noise band is +-1.5-2us. This re-samples R16.
//  K1 prep_w1r (97). K2 mega (3825, 37120B smem): conv1 | rot(nt) | w2r | w3r.
//  K3 conv2_fc1wr (904). K4 conv3 (288, BM=128). K5 fc1 (4,8,16). K6 fc2.
// Output: [logits 1024][labels 256][rotated 256*3*128*128] f32.
// ---------------------------------------------------------------------------

typedef short bf16x8 __attribute__((ext_vector_type(8)));
typedef float f32x4  __attribute__((ext_vector_type(4)));

__device__ __forceinline__ ushort f2bf(float f) {
    uint u = __float_as_uint(f);
    u += 0x7fffu + ((u >> 16) & 1u);
    return (ushort)(u >> 16);
}

__device__ __forceinline__ void nt_store4(float* p, f32x4 v) {
    __builtin_nontemporal_store(v, (f32x4*)p);
}

// async global->LDS, 16B per lane; dest linear (wave base + lane*16).
__device__ __forceinline__ void gload16(const void* g, void* l) {
    __builtin_amdgcn_global_load_lds(
        (const __attribute__((address_space(1))) unsigned int*)g,
        (__attribute__((address_space(3))) unsigned int*)l, 16, 0, 0);
}

// ---------------- K1: w1r + labels -----------------------------------------
__global__ __launch_bounds__(256) void prep_w1r(const float* __restrict__ w1,
                                                ushort* __restrict__ w1r,
                                                float* __restrict__ lab)
{
    const int bx = blockIdx.x, t = threadIdx.x;
    if (bx < 96) {                        // w1 rotated: [a*32+oc][ic*64+a8*8+b8]
        int i = bx * 256 + t;
        int n = i / 192, r = i - n * 192;
        int ic = r >> 6, a8 = (r >> 3) & 7, b8 = r & 7;
        int a = n >> 5, oc = n & 31;
        int kh, kw;
        switch (a) {
            case 0:  kh = a8;     kw = b8;     break;
            case 1:  kh = 7 - b8; kw = a8;     break;
            case 2:  kh = 7 - a8; kw = 7 - b8; break;
            default: kh = b8;     kw = 7 - a8; break;
        }
        w1r[i] = f2bf(w1[((oc * 3 + ic) * 8 + kh) * 8 + kw]);
    } else {
        lab[t] = (float)(t >> 6);
    }
}

// ---------------- K2: conv1 | rotation | w2r | w3r -------------------------
__global__ __launch_bounds__(256) void mega(const float* __restrict__ obs,
                                            const ushort* __restrict__ w1r,
                                            const float* __restrict__ b1,
                                            const float* __restrict__ w2,
                                            const float* __restrict__ w3,
                                            float* __restrict__ rot,
                                            ushort* __restrict__ act1,
                                            ushort* __restrict__ w2r,
                                            ushort* __restrict__ w3r)
{
    __shared__ __align__(16) char smem[37120];
    const int bx = blockIdx.x, t = threadIdx.x;

    if (bx < 481) {
        // ---- conv1: obs f32 -> act1 NHWC bf16, rotated weights (verified) -
        ushort* aT = (ushort*)smem;
        ushort* bT = (ushort*)(smem + 16384);
        const int m0  = bx * 128;
        const int wid = t >> 6, l = t & 63;
        const int lrow = l & 15, lk = (l >> 4) << 3;
        const int wm = (wid >> 1) * 64, wn = (wid & 1) * 64;

        int abase[4], aoff[4], bbase[4];
        #pragma unroll
        for (int j = 0; j < 4; ++j) {
            int cid = j * 256 + t;
            int row = cid >> 3, c = cid & 7;
            int m = m0 + row; m = m < 61504 ? m : 61503;
            int b = m / 961; int rem = m - b * 961;
            int p = rem / 31; int q = rem - p * 31;
            abase[j] = ((b * 3) << 14) + ((p * 4 + c) << 7) + q * 4;
            aoff[j]  = (row * 64 + c * 8) ^ ((row & 7) << 3);
            bbase[j] = row * 192 + c * 8;
        }

        f32x4 acc[4][4] = {};
        for (int ic = 0; ic < 3; ++ic) {
            #pragma unroll
            for (int j = 0; j < 4; ++j) {
                const float* src = obs + abase[j] + (ic << 14);
                float4 v0 = *(const float4*)src;
                float4 v1 = *(const float4*)(src + 4);
                bf16x8 pk;
                pk[0] = (short)f2bf(v0.x); pk[1] = (short)f2bf(v0.y);
                pk[2] = (short)f2bf(v0.z); pk[3] = (short)f2bf(v0.w);
                pk[4] = (short)f2bf(v1.x); pk[5] = (short)f2bf(v1.y);
                pk[6] = (short)f2bf(v1.z); pk[7] = (short)f2bf(v1.w);
                *(bf16x8*)&aT[aoff[j]] = pk;
            }
            #pragma unroll
            for (int j = 0; j < 4; ++j)
                *(bf16x8*)&bT[aoff[j]] = *(const bf16x8*)&w1r[bbase[j] + ic * 64];
            __syncthreads();
            #pragma unroll
            for (int s = 0; s < 2; ++s) {
                bf16x8 af[4], bv[4];
                #pragma unroll
                for (int m = 0; m < 4; ++m) {
                    int r = wm + m * 16 + lrow;
                    af[m] = *(const bf16x8*)&aT[(r * 64 + s * 32 + lk) ^ ((r & 7) << 3)];
                }
                #pragma unroll
                for (int n = 0; n < 4; ++n) {
                    int r = wn + n * 16 + lrow;
                    bv[n] = *(const bf16x8*)&bT[(r * 64 + s * 32 + lk) ^ ((r & 7) << 3)];
                }
                #pragma unroll
                for (int m = 0; m < 4; ++m)
                    #pragma unroll
                    for (int n = 0; n < 4; ++n)
                        acc[m][n] = __builtin_amdgcn_mfma_f32_16x16x32_bf16(af[m], bv[n], acc[m][n], 0, 0, 0);
            }
            __syncthreads();
        }
        #pragma unroll
        for (int m = 0; m < 4; ++m)
            #pragma unroll
            for (int j = 0; j < 4; ++j) {
                int row = m0 + wm + m * 16 + ((l >> 4) << 2) + j;
                if (row < 61504) {
                    int b = row / 961; int rem = row - b * 961;
                    int p = rem / 31;  int q = rem - p * 31;
                    #pragma unroll
                    for (int n = 0; n < 4; ++n) {
                        int col = wn + n * 16 + lrow;
                        int a = col >> 5, oc = col & 31;
                        int oh, ow;
                        switch (a) {
                            case 0:  oh = p;      ow = q;      break;
                            case 1:  oh = 30 - q; ow = p;      break;
                            case 2:  oh = 30 - p; ow = 30 - q; break;
                            default: oh = q;      ow = 30 - p; break;
                        }
                        float v = acc[m][n][j] + b1[oc];
                        v = v > 0.f ? v : 0.f;
                        act1[(((a << 6) + b) * 961 + oh * 31 + ow) * 32 + oc] = f2bf(v);
                    }
                }
            }
    } else if (bx < 3553) {
        // ---- rotation: 1-read-4-write, nt stores --------------------------
        float (*sN)[36] = (float(*)[36])smem;
        float (*sT)[33] = (float(*)[33])(smem + 4608);
        const int bb   = bx - 481;
        const int tile = bb & 15;
        const int cimg = bb >> 4;
        const int c = cimg % 3, b = cimg / 3;
        const int h0s = (tile >> 2) * 32, w0s = (tile & 3) * 32;
        const int rs = t >> 3, w4 = (t & 7) * 4;

        const float* src = obs + ((b * 3 + c) << 14);
        f32x4 v = *(const f32x4*)&src[((h0s + rs) << 7) + w0s + w4];
        *(f32x4*)&sN[rs][w4] = v;
        sT[w4 + 0][rs] = v.x; sT[w4 + 1][rs] = v.y;
        sT[w4 + 2][rs] = v.z; sT[w4 + 3][rs] = v.w;

        float* d0 = rot + (((      b) * 3 + c) << 14);
        float* d1 = rot + ((( 64 + b) * 3 + c) << 14);
        float* d2 = rot + (((128 + b) * 3 + c) << 14);
        float* d3 = rot + (((192 + b) * 3 + c) << 14);

        nt_store4(&d0[((h0s + rs) << 7) + w0s + w4], v);
        __syncthreads();
        f32x4 o;
        o.x = sT[31 - rs][w4 + 0]; o.y = sT[31 - rs][w4 + 1];
        o.z = sT[31 - rs][w4 + 2]; o.w = sT[31 - rs][w4 + 3];
        nt_store4(&d1[((96 - w0s + rs) << 7) + h0s + w4], o);
        o.x = sN[31 - rs][31 - w4 - 0]; o.y = sN[31 - rs][31 - w4 - 1];
        o.z = sN[31 - rs][31 - w4 - 2]; o.w = sN[31 - rs][31 - w4 - 3];
        nt_store4(&d2[((96 - h0s + rs) << 7) + (96 - w0s) + w4], o);
        o.x = sT[rs][31 - w4 - 0]; o.y = sT[rs][31 - w4 - 1];
        o.z = sT[rs][31 - w4 - 2]; o.w = sT[rs][31 - w4 - 3];
        nt_store4(&d3[((w0s + rs) << 7) + (96 - h0s) + w4], o);
    } else if (bx < 3681) {
        int i = (bx - 3553) * 256 + t;        // w2 -> (oc, kh, kw, ic) bf16
        int ic = i & 31, kw = (i >> 5) & 3, kh = (i >> 7) & 3, oc = i >> 9;
        w2r[i] = f2bf(w2[((oc * 32 + ic) * 4 + kh) * 4 + kw]);
    } else {
        int i = (bx - 3681) * 256 + t;        // w3 -> (oc, kh, kw, ic) bf16
        int ic = i & 63, r = i >> 6;
        int kw = r % 3, r2 = r / 3;
        int kh = r2 % 3, oc = r2 / 3;
        w3r[i] = f2bf(w3[((oc * 64 + ic) * 3 + kh) * 3 + kw]);
    }
}

// ---------------- conv body: gload_lds staging, source-swizzled ------------
template<int IC, int IH, int IW, int KH, int KW, int S, int OH, int OW>
__device__ __forceinline__ void conv_body(char* smem, int bid, int t,
                                          const ushort* __restrict__ in,
                                          const ushort* __restrict__ wr,
                                          const float* __restrict__ bias,
                                          ushort* __restrict__ out)
{
    constexpr int BK  = KW * IC;
    constexpr int NCH = BK / 8;
    constexpr int AJ  = 128 * NCH / 256;
    constexpr int BJ  = 64 * NCH / 256;
    ushort* aT = (ushort*)smem;               // 128*BK*2 B
    ushort* bT = (ushort*)(smem + 128 * BK * 2);
    const int m0 = bid * 128;
    const int wid = t >> 6, l = t & 63;
    const int lrow = l & 15, lk = (l >> 4) << 3;

    int asrc[AJ], bsrc[BJ];
    #pragma unroll
    for (int j = 0; j < AJ; ++j) {
        int tau = j * 256 + t;
        int row = tau / NCH, c = tau - row * NCH;
        int m   = m0 + row;
        int n   = m / (OH * OW); int rem = m - n * (OH * OW);
        int oh  = rem / OW; int ow = rem - oh * OW;
        asrc[j] = ((n * IH + oh * S) * IW + ow * S) * IC + (c ^ (row & 7)) * 8;
    }
    #pragma unroll
    for (int j = 0; j < BJ; ++j) {
        int tau = j * 256 + t;
        int row = tau / NCH, c = tau - row * NCH;
        bsrc[j] = row * (KH * BK) + (c ^ (row & 7)) * 8;
    }

    f32x4 acc[2][4] = {};
    for (int kh = 0; kh < KH; ++kh) {
        #pragma unroll
        for (int j = 0; j < AJ; ++j)
            gload16(in + asrc[j] + kh * (IW * IC), aT + (j * 256 + t) * 8);
        #pragma unroll
        for (int j = 0; j < BJ; ++j)
            gload16(wr + bsrc[j] + kh * BK, bT + (j * 256 + t) * 8);
        __syncthreads();
        #pragma unroll
        for (int s = 0; s < BK / 32; ++s) {
            bf16x8 af[2], bv[4];
            #pragma unroll
            for (int m = 0; m < 2; ++m) {
                int r = wid * 32 + m * 16 + lrow;
                af[m] = *(const bf16x8*)&aT[(r * BK + s * 32 + lk) ^ ((r & 7) << 3)];
            }
            #pragma unroll
            for (int n = 0; n < 4; ++n) {
                int r = n * 16 + lrow;
                bv[n] = *(const bf16x8*)&bT[(r * BK + s * 32 + lk) ^ ((r & 7) << 3)];
            }
            #pragma unroll
            for (int m = 0; m < 2; ++m)
                #pragma unroll
                for (int n = 0; n < 4; ++n)
                    acc[m][n] = __builtin_amdgcn_mfma_f32_16x16x32_bf16(af[m], bv[n], acc[m][n], 0, 0, 0);
        }
        __syncthreads();
    }
    #pragma unroll
    for (int m = 0; m < 2; ++m)
        #pragma unroll
        for (int n = 0; n < 4; ++n)
            #pragma unroll
            for (int j = 0; j < 4; ++j) {
                int row = m0 + wid * 32 + m * 16 + ((l >> 4) << 2) + j;
                int col = n * 16 + lrow;
                float v = acc[m][n][j] + bias[col];
                v = v > 0.f ? v : 0.f;
                out[row * 64 + col] = f2bf(v);
            }
}

// ---------------- K3: conv2 | fc1wr prep -----------------------------------
__global__ __launch_bounds__(256) void conv2_fc1wr(const ushort* __restrict__ act1,
                                                   const ushort* __restrict__ w2r,
                                                   const float* __restrict__ b2,
                                                   ushort* __restrict__ act2,
                                                   const float* __restrict__ fc1_w,
                                                   ushort* __restrict__ fc1wr)
{
    __shared__ __align__(16) char smem[49152];
    const int bx = blockIdx.x, t = threadIdx.x;
    if (bx < 392) {
        conv_body<32, 31, 31, 4, 4, 2, 14, 14>(smem, bx, t, act1, w2r, b2, act2);
    } else {
        // fc1_w [512][64*144] (c,p) -> bf16 (p,c), pad-145 LDS (verified)
        float* s = (float*)smem;
        const int n = bx - 392;
        #pragma unroll
        for (int j = 0; j < 9; ++j) {
            int i = (j * 256 + t) * 4;
            float4 v = *(const float4*)&fc1_w[n * 9216 + i];
            int ic = i / 144, p = i - ic * 144;
            s[ic * 145 + p + 0] = v.x; s[ic * 145 + p + 1] = v.y;
            s[ic * 145 + p + 2] = v.z; s[ic * 145 + p + 3] = v.w;
        }
        __syncthreads();
        uint* op = (uint*)(fc1wr + n * 9216);
        #pragma unroll
        for (int j = 0; j < 18; ++j) {
            int q  = j * 256 + t;
            int jj = q * 2;
            int ic = jj & 63, p = jj >> 6;
            uint lo = f2bf(s[ic * 145 + p]);
            uint hi = f2bf(s[(ic + 1) * 145 + p]);
            op[q] = lo | (hi << 16);
        }
    }
}

// ---------------- K4: conv3 (BM=128, 288 blocks) ---------------------------
__global__ __launch_bounds__(256) void conv3_k(const ushort* __restrict__ act2,
                                               const ushort* __restrict__ w3r,
                                               const float* __restrict__ b3,
                                               ushort* __restrict__ act3)
{
    __shared__ __align__(16) char smem[73728];
    conv_body<64, 14, 14, 3, 3, 1, 12, 12>(smem, blockIdx.x, threadIdx.x,
                                           act2, w3r, b3, act3);
}

// ---------------- fc1: gload_lds staging, split-K=16 -----------------------
__global__ __launch_bounds__(256) void fc1_mfma(const ushort* __restrict__ A,
                                                const ushort* __restrict__ W,
                                                float* __restrict__ hpart)
{
    __shared__ __align__(16) ushort aT[64 * 64];
    __shared__ __align__(16) ushort bT[64 * 64];
    const int t  = threadIdx.x;
    const int m0 = blockIdx.x * 64, n0 = blockIdx.y * 64;
    const int z  = blockIdx.z;                // 16 splits
    const int kb = z * 576;
    const int wid = t >> 6, l = t & 63;
    const int lrow = l & 15, lk = (l >> 4) << 3;
    const int wm = (wid >> 1) * 32, wn = (wid & 1) * 32;

    int asrcb[2], bsrcb[2];
    #pragma unroll
    for (int j = 0; j < 2; ++j) {
        int tau = j * 256 + t;
        int row = tau >> 3, c = tau & 7;
        int csw = (c ^ (row & 7)) * 8;
        asrcb[j] = (m0 + row) * 9216 + kb + csw;
        bsrcb[j] = (n0 + row) * 9216 + kb + csw;
    }

    f32x4 acc[2][2] = {};
    for (int k0 = 0; k0 < 576; k0 += 64) {
        #pragma unroll
        for (int j = 0; j < 2; ++j)
            gload16(A + asrcb[j] + k0, aT + (j * 256 + t) * 8);
        #pragma unroll
        for (int j = 0; j < 2; ++j)
            gload16(W + bsrcb[j] + k0, bT + (j * 256 + t) * 8);
        __syncthreads();
        #pragma unroll
        for (int s = 0; s < 2; ++s) {
            bf16x8 af[2], bv[2];
            #pragma unroll
            for (int m = 0; m < 2; ++m) {
                int r = wm + m * 16 + lrow;
                af[m] = *(const bf16x8*)&aT[(r * 64 + s * 32 + lk) ^ ((r & 7) << 3)];
            }
            #pragma unroll
            for (int n = 0; n < 2; ++n) {
                int r = wn + n * 16 + lrow;
                bv[n] = *(const bf16x8*)&bT[(r * 64 + s * 32 + lk) ^ ((r & 7) << 3)];
            }
            #pragma unroll
            for (int m = 0; m < 2; ++m)
                #pragma unroll
                for (int n = 0; n < 2; ++n)
                    acc[m][n] = __builtin_amdgcn_mfma_f32_16x16x32_bf16(af[m], bv[n], acc[m][n], 0, 0, 0);
        }
        __syncthreads();
    }
    #pragma unroll
    for (int m = 0; m < 2; ++m)
        #pragma unroll
        for (int n = 0; n < 2; ++n)
            #pragma unroll
            for (int j = 0; j < 4; ++j) {
                int row = m0 + wm + m * 16 + ((l >> 4) << 2) + j;
                int col = n0 + wn + n * 16 + lrow;
                hpart[(z * 256 + row) * 512 + col] = acc[m][n][j];
            }
}

// ---------------- fc2: combine 16 partials, bias, relu, final 512-dot ------
__global__ __launch_bounds__(256) void fc2_kernel(const float* __restrict__ hp,
                                                  const float* __restrict__ b1,
                                                  const float* __restrict__ W2,
                                                  const float* __restrict__ b2,
                                                  float* __restrict__ logits)
{
    __shared__ float s[512];
    const int i = blockIdx.x;
    const int t = threadIdx.x;
    for (int k = t; k < 512; k += 256) {
        float v = b1[k];
        #pragma unroll
        for (int z = 0; z < 16; ++z) v += hp[(z * 256 + i) * 512 + k];
        s[k] = v > 0.f ? v : 0.f;
    }
    __syncthreads();
    const int j = t >> 6;
    const int l = t & 63;
    float p = 0.f;
    #pragma unroll
    for (int q = 0; q < 8; ++q) p += s[l + q * 64] * W2[j * 512 + l + q * 64];
    #pragma unroll
    for (int off = 32; off > 0; off >>= 1) p += __shfl_xor(p, off);
    if (l == 0) logits[i * 4 + j] = p + b2[j];
}

// ---------------------------------------------------------------------------
extern "C" void kernel_launch(void* const* d_in, const int* in_sizes, int n_in,
                              void* d_out, int out_size, void* d_ws, size_t ws_size,
                              hipStream_t stream)
{
    const float* obs   = (const float*)d_in[0];
    const float* w1    = (const float*)d_in[1];
    const float* b1    = (const float*)d_in[2];
    const float* w2    = (const float*)d_in[3];
    const float* b2    = (const float*)d_in[4];
    const float* w3    = (const float*)d_in[5];
    const float* b3    = (const float*)d_in[6];
    const float* fc1_w = (const float*)d_in[7];
    const float* fc1_b = (const float*)d_in[8];
    const float* fc2_w = (const float*)d_in[9];
    const float* fc2_b = (const float*)d_in[10];

    float* out    = (float*)d_out;
    float* logits = out;
    float* labels = out + 1024;
    float* rot    = out + 1280;

    char* ws = (char*)d_ws;
    ushort* act1  = (ushort*)(ws);                       // 15,745,024 B (dead after conv2)
    float*  hpart = (float*) (ws);                       //  8,388,608 B (fc1/fc2 only)
    ushort* act2  = (ushort*)(ws + 15745024);            //  6,422,528 B
    ushort* act3  = (ushort*)(ws + 22167552);            //  4,718,592 B
    ushort* w2r   = (ushort*)(ws + 26886144);            //     65,536 B
    ushort* w3r   = (ushort*)(ws + 26951680);            //     73,728 B
    ushort* fc1wr = (ushort*)(ws + 27025408);            //  9,437,184 B
    ushort* w1r   = (ushort*)(ws + 40656896);            //     49,152 B

    prep_w1r<<<97, 256, 0, stream>>>(w1, w1r, labels);

    mega<<<3825, 256, 0, stream>>>(obs, w1r, b1, w2, w3,
                                   rot, act1, w2r, w3r);

    conv2_fc1wr<<<904, 256, 0, stream>>>(act1, w2r, b2, act2, fc1_w, fc1wr);

    conv3_k<<<288, 256, 0, stream>>>(act2, w3r, b3, act3);

    fc1_mfma<<<dim3(4, 8, 16), 256, 0, stream>>>(act3, fc1wr, hpart);
    fc2_kernel<<<256, 256, 0, stream>>>(hpart, fc1_b, fc2_w, fc2_b, logits);
}